// Round 1
// baseline (423.309 us; speedup 1.0000x reference)
//
#include <hip/hip_runtime.h>
#include <stdint.h>

#define NBATCH 16
#define GRP 128
#define RBITS 10
#define RADIX 1024
#define STILE 4096   // 256 threads * 16 items
#define SITEMS 16

// ---------------- small setup kernels ----------------

__global__ void count_batches(const int* __restrict__ coords, int n,
                              int* __restrict__ num) {
  __shared__ int h[NBATCH];
  const int tid = threadIdx.x;
  if (tid < NBATCH) h[tid] = 0;
  __syncthreads();
  const int i = blockIdx.x * 256 + tid;
  if (i < n) atomicAdd(&h[coords[4 * i]], 1);
  __syncthreads();
  if (tid < NBATCH) {
    int v = h[tid];
    if (v) atomicAdd(&num[tid], v);
  }
}

__global__ void prefix16(const int* __restrict__ num, int* __restrict__ bs,
                         int* __restrict__ bsp, int* __restrict__ nump,
                         int* __restrict__ bias) {
  if (threadIdx.x == 0 && blockIdx.x == 0) {
    int a = 0, b = 0;
    for (int i = 0; i < NBATCH; ++i) {
      bs[i] = a; bsp[i] = b; bias[i] = b - a;
      int npi = (num[i] + GRP - 1) / GRP * GRP;
      nump[i] = npi;
      a += num[i]; b += npi;
    }
    bs[NBATCH] = a; bsp[NBATCH] = b;
  }
}

__global__ void make_keys(const int* __restrict__ coords,
                          const int* __restrict__ shape,
                          const int* __restrict__ bias,
                          unsigned long long* __restrict__ keys,
                          int* __restrict__ win2flat, int n, int mode) {
  const int i = blockIdx.x * 256 + threadIdx.x;
  if (i >= n) return;
  const int4 c = ((const int4*)coords)[i];
  const int b = c.x, z = c.y, y = c.z, x = c.w;
  const int sz = shape[0], sy = shape[1], sx = shape[2];
  const int mx = ((sx + 15) >> 4) + 1;
  const int my = ((sy + 15) >> 4) + 1;
  const int mz = ((sz + 7) >> 3) + 1;
  const int mper = mx * my * mz;
  const int wcx = x >> 4, cix = x & 15;
  const int wcy = y >> 4, ciy = y & 15;
  const int wcz = z >> 3, ciz = z & 7;
  unsigned int key;
  if (mode == 0) {
    const int bwin = b * mper + wcx * (my * mz) + wcy * mz + wcz;
    key = (unsigned int)(bwin * 2048 + cix * 128 + ciy * 8 + ciz);
    win2flat[i] = i + bias[b];
  } else {
    const int bwin = b * mper + wcy * (mx * mz) + wcx * mz + wcz;
    key = (unsigned int)(bwin * 2048 + ciy * 128 + cix * 8 + ciz);
  }
  keys[i] = ((unsigned long long)key << 32) | (unsigned int)i;
}

__global__ void flat2win_kernel(const int* __restrict__ bs, const int* __restrict__ bsp,
                                const int* __restrict__ num, const int* __restrict__ nump,
                                int* __restrict__ out, int n_p) {
  __shared__ int sbs[NBATCH + 1], sbsp[NBATCH + 1], snum[NBATCH], snump[NBATCH];
  const int tid = threadIdx.x;
  if (tid <= NBATCH) { sbs[tid] = bs[tid]; sbsp[tid] = bsp[tid]; }
  if (tid < NBATCH) { snum[tid] = num[tid]; snump[tid] = nump[tid]; }
  __syncthreads();
  const int k = blockIdx.x * 256 + tid;
  if (k >= n_p) return;
  int b = 0;
#pragma unroll
  for (int j = 1; j < NBATCH; ++j) b += (k >= sbsp[j]) ? 1 : 0;
  const int bias = sbsp[b] - sbs[b];
  const int nb = snum[b], npb = snump[b];
  int val = k - bias;
  if (nb != npb && k >= sbsp[b] + nb) {
    if (npb != GRP) {
      val = k - GRP - bias;
    } else {
      int m = nb > 1 ? nb : 1;
      val = sbs[b] + (k - sbsp[b] - nb) % m;
    }
  }
  out[k] = val;
}

// ---------------- radix sort ----------------

__global__ void radix_hist(const unsigned int* __restrict__ src,  // view of uint64 keys
                           unsigned int* __restrict__ counts, int n, int nb, int shift) {
  __shared__ unsigned int h[RADIX];
  const int tid = threadIdx.x;
  for (int d = tid; d < RADIX; d += 256) h[d] = 0;
  __syncthreads();
  const int base = blockIdx.x * STILE;
#pragma unroll
  for (int j = 0; j < SITEMS; ++j) {
    const int e = base + j * 256 + tid;
    if (e < n) {
      const unsigned int hi = src[2 * e + 1];   // high dword = key
      atomicAdd(&h[(hi >> shift) & (RADIX - 1)], 1u);
    }
  }
  __syncthreads();
  for (int d = tid; d < RADIX; d += 256)
    counts[(size_t)d * nb + blockIdx.x] = h[d];
}

__device__ __forceinline__ unsigned int block_scan_excl(unsigned int thread_sum,
                                                        unsigned int* s) {
  const int tid = threadIdx.x;
  s[tid] = thread_sum;
  __syncthreads();
#pragma unroll
  for (int off = 1; off < 256; off <<= 1) {
    unsigned int x = (tid >= off) ? s[tid - off] : 0u;
    __syncthreads();
    s[tid] += x;
    __syncthreads();
  }
  return s[tid] - thread_sum;
}

__global__ void scan_reduce(const unsigned int* __restrict__ data,
                            unsigned int* __restrict__ partials, int L) {
  __shared__ unsigned int s[256];
  const int tid = threadIdx.x;
  const int base = blockIdx.x * 2048 + tid * 8;
  unsigned int sum = 0;
#pragma unroll
  for (int j = 0; j < 8; ++j) {
    const int idx = base + j;
    sum += (idx < L) ? data[idx] : 0u;
  }
  s[tid] = sum;
  __syncthreads();
  for (int off = 128; off > 0; off >>= 1) {
    if (tid < off) s[tid] += s[tid + off];
    __syncthreads();
  }
  if (tid == 0) partials[blockIdx.x] = s[0];
}

__global__ void scan_top(unsigned int* __restrict__ partials, int P) {
  __shared__ unsigned int s[256];
  const int tid = threadIdx.x;
  unsigned int v[8];
  unsigned int sum = 0;
  const int base = tid * 8;
#pragma unroll
  for (int j = 0; j < 8; ++j) {
    const int idx = base + j;
    v[j] = (idx < P) ? partials[idx] : 0u;
    sum += v[j];
  }
  unsigned int run = block_scan_excl(sum, s);
#pragma unroll
  for (int j = 0; j < 8; ++j) {
    const int idx = base + j;
    if (idx < P) partials[idx] = run;
    run += v[j];
  }
}

__global__ void scan_apply(unsigned int* __restrict__ data,
                           const unsigned int* __restrict__ partials, int L) {
  __shared__ unsigned int s[256];
  const int tid = threadIdx.x;
  const int base = blockIdx.x * 2048 + tid * 8;
  unsigned int v[8];
  unsigned int sum = 0;
#pragma unroll
  for (int j = 0; j < 8; ++j) {
    const int idx = base + j;
    v[j] = (idx < L) ? data[idx] : 0u;
    sum += v[j];
  }
  unsigned int run = block_scan_excl(sum, s) + partials[blockIdx.x];
#pragma unroll
  for (int j = 0; j < 8; ++j) {
    const int idx = base + j;
    if (idx < L) data[idx] = run;
    run += v[j];
  }
}

__global__ void radix_scatter(const unsigned long long* __restrict__ src,
                              unsigned long long* __restrict__ dst,
                              int* __restrict__ out_idx,
                              const unsigned int* __restrict__ counts,
                              int n, int nb, int shift) {
  __shared__ unsigned int sbase[RADIX];
  __shared__ unsigned int wh[4 * RADIX];
  const int tid = threadIdx.x;
  const int blk = blockIdx.x;
  for (int d = tid; d < RADIX; d += 256) sbase[d] = counts[(size_t)d * nb + blk];
  for (int d = tid; d < 4 * RADIX; d += 256) wh[d] = 0;
  __syncthreads();
  const int lane = tid & 63;
  const int w = tid >> 6;
  const unsigned long long lt = (((unsigned long long)1) << lane) - 1ull;
  const int base = blk * STILE;
  for (int j = 0; j < SITEMS; ++j) {
    const int e = base + j * 256 + tid;
    const bool valid = e < n;
    const unsigned long long p = valid ? src[e] : 0ull;
    const unsigned int d = (((unsigned int)(p >> 32)) >> shift) & (RADIX - 1);
    const unsigned long long vm = __ballot(valid ? 1 : 0);
    unsigned long long m = vm;
#pragma unroll
    for (int bbit = 0; bbit < RBITS; ++bbit) {
      const unsigned long long bb = __ballot((d >> bbit) & 1);
      m &= ((d >> bbit) & 1) ? bb : ~bb;
    }
    const unsigned int lr = (unsigned int)__popcll(m & lt);
    const unsigned int cnt = (unsigned int)__popcll(m);
    const bool leader = valid && (lr == 0);
    if (leader) wh[w * RADIX + d] = cnt;
    __syncthreads();
    if (valid) {
      unsigned int before = 0;
      for (int w2 = 0; w2 < w; ++w2) before += wh[w2 * RADIX + d];
      const unsigned int pos = sbase[d] + before + lr;
      if (out_idx) out_idx[pos] = (int)(unsigned int)p;
      else dst[pos] = p;
    }
    __syncthreads();
    if (leader) {
      atomicAdd(&sbase[d], cnt);
      wh[w * RADIX + d] = 0;
    }
    __syncthreads();
  }
}

// ---------------- host ----------------

static inline int ceil_div(int a, int b) { return (a + b - 1) / b; }

extern "C" void kernel_launch(void* const* d_in, const int* in_sizes, int n_in,
                              void* d_out, int out_size, void* d_ws, size_t ws_size,
                              hipStream_t stream) {
  const int* coords = (const int*)d_in[0];
  const int* shape = (const int*)d_in[2];
  const int n = in_sizes[0] / 4;
  const int n_p = out_size - 3 * n;

  int* out = (int*)d_out;
  int* flat2win = out;
  int* win2flat = out + n_p;
  int* idx_x = out + (size_t)n_p + n;
  int* idx_y = out + (size_t)n_p + 2 * (size_t)n;

  const int NB = ceil_div(n, STILE);
  const int L = NB * RADIX;
  const int NS = ceil_div(L, 2048);

  char* ws = (char*)d_ws;
  size_t off = 0;
  auto take = [&](size_t bytes) -> void* {
    void* p = (void*)(ws + off);
    off += (bytes + 255) & ~(size_t)255;
    return p;
  };
  unsigned long long* A = (unsigned long long*)take((size_t)n * 8);
  unsigned long long* B = (unsigned long long*)take((size_t)n * 8);
  unsigned int* counts = (unsigned int*)take((size_t)L * 4);
  unsigned int* partials = (unsigned int*)take((size_t)NS * 4 + 256);
  int* num = (int*)take(64);
  int* bs = (int*)take(128);
  int* bsp = (int*)take(128);
  int* nump = (int*)take(64);
  int* bias = (int*)take(64);
  (void)ws_size; (void)n_in;

  hipMemsetAsync(num, 0, NBATCH * sizeof(int), stream);
  count_batches<<<ceil_div(n, 256), 256, 0, stream>>>(coords, n, num);
  prefix16<<<1, 64, 0, stream>>>(num, bs, bsp, nump, bias);
  make_keys<<<ceil_div(n, 256), 256, 0, stream>>>(coords, shape, bias, A, win2flat, n, 0);
  flat2win_kernel<<<ceil_div(n_p, 256), 256, 0, stream>>>(bs, bsp, num, nump, flat2win, n_p);

  auto run_sort = [&](int* oidx) {
    unsigned long long* src = A;
    unsigned long long* dst = B;
    for (int pass = 0; pass < 3; ++pass) {
      const int shift = RBITS * pass;
      radix_hist<<<NB, 256, 0, stream>>>((const unsigned int*)src, counts, n, NB, shift);
      scan_reduce<<<NS, 256, 0, stream>>>(counts, partials, L);
      scan_top<<<1, 256, 0, stream>>>(partials, NS);
      scan_apply<<<NS, 256, 0, stream>>>(counts, partials, L);
      radix_scatter<<<NB, 256, 0, stream>>>(src, dst, (pass == 2) ? oidx : nullptr,
                                            counts, n, NB, shift);
      unsigned long long* t = src; src = dst; dst = t;
    }
  };

  run_sort(idx_x);
  make_keys<<<ceil_div(n, 256), 256, 0, stream>>>(coords, shape, bias, A, win2flat, n, 1);
  run_sort(idx_y);
}

// Round 2
// 385.397 us; speedup vs baseline: 1.0984x; 1.0984x over previous
//
#include <hip/hip_runtime.h>
#include <stdint.h>

#define NBATCH 16
#define GRP 128
#define RBITS 10
#define RADIX 1024
#define STILE 4096   // 256 threads * 16 items
#define SITEMS 16
#define SCAN_CHUNK 2048

// ---------------- setup ----------------

// batch ids are sorted (b = repeat(arange(16), counts)): find segment starts.
__global__ void find_starts(const int* __restrict__ coords, int n,
                            int* __restrict__ start /*17*/) {
  const int i = blockIdx.x * 256 + threadIdx.x;
  if (i >= n) return;
  const int b = coords[4 * i];
  if (i == 0) {
    for (int v = 0; v <= b; ++v) start[v] = 0;
  }
  if (i == n - 1) {
    for (int v = b + 1; v <= NBATCH; ++v) start[v] = n;
  } else {
    const int b2 = coords[4 * (i + 1)];
    if (b2 != b)
      for (int v = b + 1; v <= b2; ++v) start[v] = i + 1;
  }
}

__global__ void prefix16(const int* __restrict__ bs_in, int* __restrict__ bs,
                         int* __restrict__ bsp, int* __restrict__ num,
                         int* __restrict__ nump) {
  if (threadIdx.x == 0 && blockIdx.x == 0) {
    int b = 0;
    for (int i = 0; i < NBATCH; ++i) {
      const int s = bs_in[i];
      const int ni = bs_in[i + 1] - s;
      bs[i] = s; bsp[i] = b;
      num[i] = ni;
      const int npi = (ni + GRP - 1) / GRP * GRP;
      nump[i] = npi;
      b += npi;
    }
    bs[NBATCH] = bs_in[NBATCH];
    bsp[NBATCH] = b;
  }
}

// fused: make keys (mode 0) + win2flat + flat2win
__global__ void keys_w2f_f2w(const int* __restrict__ coords,
                             const int* __restrict__ shape,
                             const int* __restrict__ bs, const int* __restrict__ bsp,
                             const int* __restrict__ num, const int* __restrict__ nump,
                             unsigned long long* __restrict__ keys,
                             int* __restrict__ win2flat, int* __restrict__ f2w,
                             int n, int n_p) {
  __shared__ int sbs[NBATCH + 1], sbsp[NBATCH + 1], snum[NBATCH], snump[NBATCH];
  const int tid = threadIdx.x;
  if (tid <= NBATCH) { sbs[tid] = bs[tid]; sbsp[tid] = bsp[tid]; }
  if (tid < NBATCH) { snum[tid] = num[tid]; snump[tid] = nump[tid]; }
  __syncthreads();
  const int i = blockIdx.x * 256 + tid;
  if (i < n) {
    const int4 c = ((const int4*)coords)[i];
    const int b = c.x, z = c.y, y = c.z, x = c.w;
    const int sz = shape[0], sy = shape[1], sx = shape[2];
    const int mx = ((sx + 15) >> 4) + 1;
    const int my = ((sy + 15) >> 4) + 1;
    const int mz = ((sz + 7) >> 3) + 1;
    const int mper = mx * my * mz;
    const int wcx = x >> 4, cix = x & 15;
    const int wcy = y >> 4, ciy = y & 15;
    const int wcz = z >> 3, ciz = z & 7;
    const int bwin = b * mper + wcx * (my * mz) + wcy * mz + wcz;
    const unsigned int key = (unsigned int)(bwin * 2048 + cix * 128 + ciy * 8 + ciz);
    keys[i] = ((unsigned long long)key << 32) | (unsigned int)i;
    win2flat[i] = i + (sbsp[b] - sbs[b]);
  }
  if (i < n_p) {
    const int k = i;
    int b = 0;
#pragma unroll
    for (int j = 1; j < NBATCH; ++j) b += (k >= sbsp[j]) ? 1 : 0;
    const int bias = sbsp[b] - sbs[b];
    const int nb = snum[b], npb = snump[b];
    int val = k - bias;
    if (nb != npb && k >= sbsp[b] + nb) {
      if (npb != GRP) {
        val = k - GRP - bias;
      } else {
        const int m = nb > 1 ? nb : 1;
        val = sbs[b] + (k - sbsp[b] - nb) % m;
      }
    }
    f2w[k] = val;
  }
}

__global__ void make_keys_y(const int* __restrict__ coords,
                            const int* __restrict__ shape,
                            unsigned long long* __restrict__ keys, int n) {
  const int i = blockIdx.x * 256 + threadIdx.x;
  if (i >= n) return;
  const int4 c = ((const int4*)coords)[i];
  const int b = c.x, z = c.y, y = c.z, x = c.w;
  const int sz = shape[0], sy = shape[1], sx = shape[2];
  const int mx = ((sx + 15) >> 4) + 1;
  const int my = ((sy + 15) >> 4) + 1;
  const int mz = ((sz + 7) >> 3) + 1;
  const int mper = mx * my * mz;
  const int wcx = x >> 4, cix = x & 15;
  const int wcy = y >> 4, ciy = y & 15;
  const int wcz = z >> 3, ciz = z & 7;
  const int bwin = b * mper + wcy * (mx * mz) + wcx * mz + wcz;
  const unsigned int key = (unsigned int)(bwin * 2048 + ciy * 128 + cix * 8 + ciz);
  keys[i] = ((unsigned long long)key << 32) | (unsigned int)i;
}

// ---------------- radix sort ----------------

__global__ void radix_hist(const unsigned long long* __restrict__ src,
                           unsigned int* __restrict__ counts, int n, int nb, int shift) {
  __shared__ unsigned int h[RADIX];
  const int tid = threadIdx.x;
  for (int d = tid; d < RADIX; d += 256) h[d] = 0;
  __syncthreads();
  const int base = blockIdx.x * STILE;
#pragma unroll
  for (int j = 0; j < SITEMS; ++j) {
    const int e = base + j * 256 + tid;
    if (e < n) {
      const unsigned long long p = src[e];
      atomicAdd(&h[(((unsigned int)(p >> 32)) >> shift) & (RADIX - 1)], 1u);
    }
  }
  __syncthreads();
  for (int d = tid; d < RADIX; d += 256)
    counts[(size_t)d * nb + blockIdx.x] = h[d];
}

__device__ __forceinline__ unsigned int block_scan_excl(unsigned int thread_sum,
                                                        unsigned int* s) {
  const int tid = threadIdx.x;
  s[tid] = thread_sum;
  __syncthreads();
#pragma unroll
  for (int off = 1; off < 256; off <<= 1) {
    unsigned int x = (tid >= off) ? s[tid - off] : 0u;
    __syncthreads();
    s[tid] += x;
    __syncthreads();
  }
  return s[tid] - thread_sum;
}

// single-kernel decoupled-lookback exclusive scan over L uints (in place)
__global__ void scan_chained(unsigned int* __restrict__ data, int L,
                             unsigned long long* __restrict__ desc) {
  __shared__ unsigned int s[256];
  __shared__ unsigned int s_base;
  const int tid = threadIdx.x;
  const int blk = blockIdx.x;
  const int base = blk * SCAN_CHUNK + tid * 8;
  unsigned int v[8], sum = 0;
#pragma unroll
  for (int j = 0; j < 8; ++j) {
    const int idx = base + j;
    v[j] = (idx < L) ? data[idx] : 0u;
    sum += v[j];
  }
  const unsigned int excl = block_scan_excl(sum, s);
  const unsigned int total = s[255];
  if (tid == 0) {
    const unsigned long long tag = (blk == 0) ? (2ull << 32) : (1ull << 32);
    __hip_atomic_store(&desc[blk], tag | total, __ATOMIC_RELEASE,
                       __HIP_MEMORY_SCOPE_AGENT);
    if (blk == 0) s_base = 0;
  }
  if (blk > 0 && tid < 64) {
    unsigned int run = 0;
    int jb = blk - 1;
    for (;;) {
      const int j = jb - tid;  // lane 0 = nearest predecessor
      unsigned long long d;
      if (j >= 0) {
        do {
          d = __hip_atomic_load(&desc[j], __ATOMIC_ACQUIRE, __HIP_MEMORY_SCOPE_AGENT);
        } while ((d >> 32) == 0);
      } else {
        d = (2ull << 32);  // sentinel: prefix 0
      }
      const unsigned long long m2 = __ballot((d >> 32) == 2);
      const int f = m2 ? __builtin_ctzll(m2) : 64;
      unsigned int contrib = (tid <= f) ? (unsigned int)d : 0u;
#pragma unroll
      for (int o = 32; o > 0; o >>= 1) contrib += __shfl_down(contrib, o, 64);
      run += __shfl(contrib, 0, 64);
      if (m2) break;
      jb -= 64;
    }
    if (tid == 0) {
      __hip_atomic_store(&desc[blk], (2ull << 32) | (run + total),
                         __ATOMIC_RELEASE, __HIP_MEMORY_SCOPE_AGENT);
      s_base = run;
    }
  }
  __syncthreads();
  unsigned int off = s_base + excl;
#pragma unroll
  for (int j = 0; j < 8; ++j) {
    const int idx = base + j;
    if (idx < L) data[idx] = off;
    off += v[j];
  }
}

__global__ void radix_scatter(const unsigned long long* __restrict__ src,
                              unsigned long long* __restrict__ dst,
                              int* __restrict__ out_idx,
                              const unsigned int* __restrict__ counts,
                              int n, int nb, int shift) {
  __shared__ unsigned int sbase[RADIX];
  __shared__ unsigned int wh[4 * RADIX];
  const int tid = threadIdx.x;
  const int blk = blockIdx.x;
  for (int d = tid; d < RADIX; d += 256) sbase[d] = counts[(size_t)d * nb + blk];
  for (int d = tid; d < 4 * RADIX; d += 256) wh[d] = 0;
  __syncthreads();
  const int lane = tid & 63;
  const int w = tid >> 6;
  const unsigned long long lt = (((unsigned long long)1) << lane) - 1ull;
  const int base = blk * STILE;
  for (int j = 0; j < SITEMS; ++j) {
    const int e = base + j * 256 + tid;
    const bool valid = e < n;
    const unsigned long long p = valid ? src[e] : 0ull;
    const unsigned int d = (((unsigned int)(p >> 32)) >> shift) & (RADIX - 1);
    unsigned long long m = __ballot(valid ? 1 : 0);
#pragma unroll
    for (int bbit = 0; bbit < RBITS; ++bbit) {
      const unsigned long long bb = __ballot((d >> bbit) & 1);
      m &= ((d >> bbit) & 1) ? bb : ~bb;
    }
    const unsigned int lr = (unsigned int)__popcll(m & lt);
    const unsigned int cnt = (unsigned int)__popcll(m);
    const bool leader = valid && (lr == 0);
    if (leader) wh[w * RADIX + d] = cnt;
    __syncthreads();
    if (valid) {
      unsigned int before = 0;
      for (int w2 = 0; w2 < w; ++w2) before += wh[w2 * RADIX + d];
      const unsigned int pos = sbase[d] + before + lr;
      if (out_idx) out_idx[pos] = (int)(unsigned int)p;
      else dst[pos] = p;
    }
    __syncthreads();
    if (leader) {
      atomicAdd(&sbase[d], cnt);
      wh[w * RADIX + d] = 0;
    }
    __syncthreads();
  }
}

// ---------------- host ----------------

static inline int ceil_div(int a, int b) { return (a + b - 1) / b; }

extern "C" void kernel_launch(void* const* d_in, const int* in_sizes, int n_in,
                              void* d_out, int out_size, void* d_ws, size_t ws_size,
                              hipStream_t stream) {
  const int* coords = (const int*)d_in[0];
  const int* shape = (const int*)d_in[2];
  const int n = in_sizes[0] / 4;
  const int n_p = out_size - 3 * n;

  int* out = (int*)d_out;
  int* flat2win = out;
  int* win2flat = out + n_p;
  int* idx_x = out + (size_t)n_p + n;
  int* idx_y = out + (size_t)n_p + 2 * (size_t)n;

  const int NB = ceil_div(n, STILE);
  const int L = NB * RADIX;
  const int NS = ceil_div(L, SCAN_CHUNK);

  char* ws = (char*)d_ws;
  size_t off = 0;
  auto take = [&](size_t bytes) -> void* {
    void* p = (void*)(ws + off);
    off += (bytes + 255) & ~(size_t)255;
    return p;
  };
  unsigned long long* A = (unsigned long long*)take((size_t)n * 8);
  unsigned long long* B = (unsigned long long*)take((size_t)n * 8);
  unsigned int* counts = (unsigned int*)take((size_t)L * 4);
  unsigned long long* desc = (unsigned long long*)take((size_t)6 * NS * 8);
  int* starts = (int*)take(128);
  int* bs = (int*)take(128);
  int* bsp = (int*)take(128);
  int* num = (int*)take(64);
  int* nump = (int*)take(64);
  (void)ws_size; (void)n_in;

  hipMemsetAsync(desc, 0, (size_t)6 * NS * 8, stream);
  find_starts<<<ceil_div(n, 256), 256, 0, stream>>>(coords, n, starts);
  prefix16<<<1, 64, 0, stream>>>(starts, bs, bsp, num, nump);
  const int nmax = (n > n_p) ? n : n_p;
  keys_w2f_f2w<<<ceil_div(nmax, 256), 256, 0, stream>>>(
      coords, shape, bs, bsp, num, nump, A, win2flat, flat2win, n, n_p);

  int desc_slice = 0;
  auto run_sort = [&](int* oidx) {
    unsigned long long* src = A;
    unsigned long long* dst = B;
    for (int pass = 0; pass < 3; ++pass) {
      const int shift = RBITS * pass;
      radix_hist<<<NB, 256, 0, stream>>>(src, counts, n, NB, shift);
      scan_chained<<<NS, 256, 0, stream>>>(counts, L, desc + (size_t)desc_slice * NS);
      ++desc_slice;
      radix_scatter<<<NB, 256, 0, stream>>>(src, dst, (pass == 2) ? oidx : nullptr,
                                            counts, n, NB, shift);
      unsigned long long* t = src; src = dst; dst = t;
    }
  };

  run_sort(idx_x);
  make_keys_y<<<ceil_div(n, 256), 256, 0, stream>>>(coords, shape, A, n);
  run_sort(idx_y);
}